// Round 2
// baseline (212.015 us; speedup 1.0000x reference)
//
#include <hip/hip_runtime.h>
#include <hip/hip_bf16.h>
#include <math.h>

// prim_caps [256,1152,8], W [1,1152,10,16,8], out v [256,10,16,1] (40960)
// dtype (bf16 vs fp32) detected at runtime; see detect_kernel.
#define B_SZ 256
#define R_SZ 1152
#define C_SZ 10
#define D_SZ 16
#define NSPLIT 9      // split-R chunks for s kernel (1152/9 = 128 r per chunk)
#define RCHUNK 128
#define RSTAGE 32
#define BT 32
#define PSTRIDE 264   // float stride per b-row in s_kernel LDS (mult of 8 -> b128 ok; %32=8 -> 2-way bank only)

// ws layout (floats): flag@0(int), c_coef@16, b_log@11536, v_buf@23056, partials@64016
#define OFF_C 16
#define OFF_B 11536
#define OFF_V 23056
#define OFF_P 64016

__device__ __forceinline__ void unpack8_bf16(uint4 u, float* f) {
    unsigned x;
    x = u.x; f[0] = __uint_as_float(x << 16); f[1] = __uint_as_float(x & 0xFFFF0000u);
    x = u.y; f[2] = __uint_as_float(x << 16); f[3] = __uint_as_float(x & 0xFFFF0000u);
    x = u.z; f[4] = __uint_as_float(x << 16); f[5] = __uint_as_float(x & 0xFFFF0000u);
    x = u.w; f[6] = __uint_as_float(x << 16); f[7] = __uint_as_float(x & 0xFFFF0000u);
}

// load 8 consecutive elements (row `idx` of an 8-element-row array) as fp32
__device__ __forceinline__ void load_row8(const void* base, int idx, int isbf, float* f) {
    if (isbf) {
        uint4 u = ((const uint4*)base)[idx];
        unpack8_bf16(u, f);
    } else {
        const float4* p = (const float4*)base + (size_t)idx * 2;
        float4 a = p[0], b = p[1];
        f[0]=a.x; f[1]=a.y; f[2]=a.z; f[3]=a.w;
        f[4]=b.x; f[5]=b.y; f[6]=b.z; f[7]=b.w;
    }
}

// Decide bf16 vs fp32: low-half-as-bf16 exponent of genuine bf16 N(0,1) data is
// ~always in [90,141]; for fp32 data those bits are mantissa bits (uniform).
__global__ void detect_kernel(const unsigned* __restrict__ P, int* __restrict__ flag) {
    const int tid = threadIdx.x;
    int cnt = 0;
    #pragma unroll
    for (int k = 0; k < 4; ++k) {
        unsigned w = P[tid + k * 64];
        unsigned e0 = (w >> 7) & 0xFFu;
        cnt += (e0 >= 90u && e0 <= 141u) ? 1 : 0;
    }
    #pragma unroll
    for (int m = 1; m < 64; m <<= 1) cnt += __shfl_xor(cnt, m);
    if (tid == 0) *flag = (cnt >= 200) ? 1 : 0;
}

// s[b,c,d] = sum_r c[r,c] * sum_i W[r,c,d,i]*p[b,r,i]   (split over NSPLIT r-chunks)
__global__ __launch_bounds__(256) void s_kernel(
    const void* __restrict__ Pv, const void* __restrict__ Wv,
    const float* __restrict__ c_coef, float* __restrict__ partials,
    const int* __restrict__ flag, int uniform)
{
    __shared__ float wlds[RSTAGE * 16 * 8];   // [rr][d][i]  16 KB
    __shared__ float plds[BT * PSTRIDE];      // [bb*264 + rr*8 + i]  33.8 KB
    __shared__ float clds[RSTAGE];

    const int isbf = *flag;
    const int tid = threadIdx.x;
    const int rs  = blockIdx.x;   // r chunk
    const int bt  = blockIdx.y;   // batch tile
    const int c   = blockIdx.z;
    const int bb  = tid >> 3;
    const int dd  = tid & 7;

    float acc0 = 0.f, acc1 = 0.f;

    for (int st = 0; st < RCHUNK / RSTAGE; ++st) {
        const int r0 = rs * RCHUNK + st * RSTAGE;
        __syncthreads();
        // stage W: 512 rows of 8
        #pragma unroll
        for (int k = 0; k < 2; ++k) {
            int u = tid + k * 256;
            int rr = u >> 4, col = u & 15;
            float f[8];
            load_row8(Wv, ((r0 + rr) * C_SZ + c) * 16 + col, isbf, f);
            #pragma unroll
            for (int i = 0; i < 8; ++i) wlds[u * 8 + i] = f[i];
        }
        // stage P: 1024 rows of 8
        #pragma unroll
        for (int k = 0; k < 4; ++k) {
            int u = tid + k * 256;
            int pb = u >> 5, rr = u & 31;
            float f[8];
            load_row8(Pv, (bt * BT + pb) * R_SZ + (r0 + rr), isbf, f);
            #pragma unroll
            for (int i = 0; i < 8; ++i) plds[pb * PSTRIDE + rr * 8 + i] = f[i];
        }
        if (!uniform && tid < RSTAGE) clds[tid] = c_coef[(r0 + tid) * C_SZ + c];
        __syncthreads();

        for (int rr = 0; rr < RSTAGE; ++rr) {
            const float* pr = &plds[bb * PSTRIDE + rr * 8];
            const float* w0 = &wlds[(rr * 16 + dd) * 8];
            const float* w1 = &wlds[(rr * 16 + dd + 8) * 8];
            float d0 = 0.f, d1 = 0.f;
            #pragma unroll
            for (int i = 0; i < 8; ++i) {
                d0 = fmaf(pr[i], w0[i], d0);
                d1 = fmaf(pr[i], w1[i], d1);
            }
            const float cr = uniform ? 1.0f : clds[rr];
            acc0 = fmaf(cr, d0, acc0);
            acc1 = fmaf(cr, d1, acc1);
        }
    }
    if (uniform) { acc0 *= 0.1f; acc1 *= 0.1f; }

    const int b = bt * BT + bb;
    const int base = rs * 40960 + (b * C_SZ + c) * D_SZ;
    partials[base + dd]     = acc0;
    partials[base + dd + 8] = acc1;
}

// sum split-K partials, squash along d; final iter writes out (dtype per flag)
__global__ __launch_bounds__(256) void squash_kernel(
    const float* __restrict__ partials, float* __restrict__ v_buf,
    void* __restrict__ outv, const int* __restrict__ flag, int last)
{
    const int idx = blockIdx.x * 256 + threadIdx.x;   // (b*10+c)*16+d
    float s = 0.f;
    #pragma unroll
    for (int k = 0; k < NSPLIT; ++k) s += partials[k * 40960 + idx];
    float sq = s * s;
    sq += __shfl_xor(sq, 1);
    sq += __shfl_xor(sq, 2);
    sq += __shfl_xor(sq, 4);
    sq += __shfl_xor(sq, 8);
    const float v = s * sqrtf(sq) / (1.0f + sq);
    v_buf[idx] = v;
    if (last) {
        if (*flag) ((__hip_bfloat16*)outv)[idx] = __float2bfloat16(v);
        else       ((float*)outv)[idx] = v;
    }
}

// b_log[r,c] += mean_b sum_d (sum_i W[r,c,d,i]p[b,r,i]) * v[b,c,d]; c_coef = softmax_c
__global__ __launch_bounds__(192) void agree_kernel(
    const void* __restrict__ Pv, const void* __restrict__ Wv,
    const float* __restrict__ v_buf, float* __restrict__ b_log,
    float* __restrict__ c_coef, const int* __restrict__ flag, int first)
{
    __shared__ float plds[B_SZ * 8];   // p[:, r, :]  8 KB
    __shared__ float sm[C_SZ];

    const int isbf = *flag;
    const int tid = threadIdx.x;
    const int r = blockIdx.x;
    for (int u = tid; u < B_SZ; u += 192) {
        float f[8];
        load_row8(Pv, u * R_SZ + r, isbf, f);
        #pragma unroll
        for (int i = 0; i < 8; ++i) plds[u * 8 + i] = f[i];
    }

    const int cc = tid >> 4;
    const int dv = tid & 15;
    const bool active = tid < 160;
    float wf[8];
    if (active) load_row8(Wv, (r * C_SZ + cc) * 16 + dv, isbf, wf);
    __syncthreads();

    float acc = 0.f;
    if (active) {
        for (int b = 0; b < B_SZ; ++b) {
            const float* pf = &plds[b * 8];
            float uh = 0.f;
            #pragma unroll
            for (int i = 0; i < 8; ++i) uh = fmaf(pf[i], wf[i], uh);
            acc = fmaf(uh, v_buf[(b * C_SZ + cc) * D_SZ + dv], acc);
        }
    }
    acc += __shfl_xor(acc, 1);
    acc += __shfl_xor(acc, 2);
    acc += __shfl_xor(acc, 4);
    acc += __shfl_xor(acc, 8);

    if (active && dv == 0) {
        const float a = acc * (1.0f / 256.0f);
        const float bprev = first ? 0.f : b_log[r * C_SZ + cc];
        const float bc = bprev + a;
        b_log[r * C_SZ + cc] = bc;
        sm[cc] = bc;
    }
    __syncthreads();
    if (tid < C_SZ) {
        float m = sm[0];
        #pragma unroll
        for (int j = 1; j < C_SZ; ++j) m = fmaxf(m, sm[j]);
        float den = 0.f;
        #pragma unroll
        for (int j = 0; j < C_SZ; ++j) den += __expf(sm[j] - m);
        c_coef[r * C_SZ + tid] = __expf(sm[tid] - m) / den;
    }
}

extern "C" void kernel_launch(void* const* d_in, const int* in_sizes, int n_in,
                              void* d_out, int out_size, void* d_ws, size_t ws_size,
                              hipStream_t stream)
{
    const void* Pv = d_in[0];
    const void* Wv = d_in[1];
    float* ws     = (float*)d_ws;
    int*   flag   = (int*)d_ws;
    float* c_coef = ws + OFF_C;
    float* b_log  = ws + OFF_B;
    float* v_buf  = ws + OFF_V;
    float* parts  = ws + OFF_P;

    detect_kernel<<<1, 64, 0, stream>>>((const unsigned*)Pv, flag);

    const dim3 sg(NSPLIT, 8, C_SZ);
    // iteration 0: c uniform (=0.1)
    s_kernel<<<sg, 256, 0, stream>>>(Pv, Wv, c_coef, parts, flag, 1);
    squash_kernel<<<160, 256, 0, stream>>>(parts, v_buf, d_out, flag, 0);
    // iteration 1
    agree_kernel<<<R_SZ, 192, 0, stream>>>(Pv, Wv, v_buf, b_log, c_coef, flag, 1);
    s_kernel<<<sg, 256, 0, stream>>>(Pv, Wv, c_coef, parts, flag, 0);
    squash_kernel<<<160, 256, 0, stream>>>(parts, v_buf, d_out, flag, 0);
    // iteration 2 (final v -> d_out; last logit update skipped)
    agree_kernel<<<R_SZ, 192, 0, stream>>>(Pv, Wv, v_buf, b_log, c_coef, flag, 0);
    s_kernel<<<sg, 256, 0, stream>>>(Pv, Wv, c_coef, parts, flag, 0);
    squash_kernel<<<160, 256, 0, stream>>>(parts, v_buf, d_out, flag, 1);
}

// Round 7
// 208.537 us; speedup vs baseline: 1.0167x; 1.0167x over previous
//
#include <hip/hip_runtime.h>
#include <hip/hip_bf16.h>
#include <math.h>

// DigitCaps routing. PROVEN (rounds 2,6): P/W/out are all FP32.
//   P [256][1152*8] f32, W [1152][10][16][8] f32, out v [256][10][16] f32.
// MFMA via hi/lo bf16 split (x = hi+lo; a*b ~ ah*bh + ah*bl + al*bh, ~2^-17).
// c_coef folded into B in fp32 (Bc = c*W) before splitting -> exact.
// Round 7 fix: round 6 overlapped Ph/Pl (uint2 counted as 4B). Offsets redone.

typedef __bf16 bf16x8 __attribute__((ext_vector_type(8)));
typedef float v4f __attribute__((ext_vector_type(4)));

__device__ __forceinline__ float b2f(unsigned short u) {
    return __uint_as_float(((unsigned)u) << 16);
}
__device__ __forceinline__ unsigned short f2b(float f) {   // RNE, finite only
    unsigned x = __float_as_uint(f);
    return (unsigned short)((x + 0x7FFFu + ((x >> 16) & 1u)) >> 16);
}
__device__ __forceinline__ void split4(float4 x, unsigned short* h, unsigned short* l) {
    const float* xf = (const float*)&x;
    #pragma unroll
    for (int i = 0; i < 4; ++i) {
        h[i] = f2b(xf[i]);
        l[i] = f2b(xf[i] - b2f(h[i]));
    }
}
__device__ __forceinline__ uint2 pack4(const unsigned short* s) {
    uint2 w;
    w.x = s[0] | ((unsigned)s[1] << 16);
    w.y = s[2] | ((unsigned)s[3] << 16);
    return w;
}

// ---- one-time hi/lo split of P (589824 float4s) ----
__global__ __launch_bounds__(256) void split_p_kernel(
    const float4* __restrict__ P4, uint2* __restrict__ Ph, uint2* __restrict__ Pl)
{
    const int idx = blockIdx.x * 256 + threadIdx.x;    // 0..589823
    unsigned short h[4], l[4];
    split4(P4[idx], h, l);
    Ph[idx] = pack4(h);
    Pl[idx] = pack4(l);
}

// ---- one-time hi/lo split of W (368640 float4s) ----
__global__ __launch_bounds__(256) void split_w_kernel(
    const float4* __restrict__ W4, uint2* __restrict__ Wh, uint2* __restrict__ Wl)
{
    const int idx = blockIdx.x * 256 + threadIdx.x;    // 0..368639
    unsigned short h[4], l[4];
    split4(W4[idx], h, l);
    Wh[idx] = pack4(h);
    Wl[idx] = pack4(l);
}

// ---- Bc = c_coef[r,c] * W (fp32 exact), split hi/lo ----
__global__ __launch_bounds__(256) void bc_kernel(
    const float4* __restrict__ W4, const float* __restrict__ Cc,
    uint2* __restrict__ Bh, uint2* __restrict__ Bl)
{
    const int idx = blockIdx.x * 256 + threadIdx.x;    // float4 units
    const int r = idx / 320;                           // 320 float4 per r
    const int c = (idx >> 5) % 10;                     // 32 float4 per (r,c)
    const float cs = Cc[r * 10 + c];
    float4 w = W4[idx];
    w.x *= cs; w.y *= cs; w.z *= cs; w.w *= cs;
    unsigned short h[4], l[4];
    split4(w, h, l);
    Bh[idx] = pack4(h);
    Bl[idx] = pack4(l);
}

// ---- MFMA s-GEMM + fused squash. block=(c, 16-b tile); split-K over 4 waves.
// A-frag: lane(m=lm,q): uint4 (b0+lm)*1152 + kk*4+q = P[b0+lm][k=kk*32+q*8..+7]
// B-frag: uint4 (q*10+c)*16+lm + kk*640 = W[r=kk*4+q][c][d=lm][0..7]
// D: acc[r] = s[b=b0+q*4+r][d=lm]  (C/D: row=quad*4+reg, col=lane&15)
__global__ __launch_bounds__(256) void sgemm_kernel(
    const uint4* __restrict__ Ah, const uint4* __restrict__ Al,
    const uint4* __restrict__ Bh, const uint4* __restrict__ Bl,
    float* __restrict__ v_buf, float* __restrict__ outb,
    int uniform, int last)
{
    __shared__ float comb[4][64][4];
    const int tid = threadIdx.x;
    const int wave = tid >> 6, lane = tid & 63;
    const int lm = lane & 15, q = lane >> 4;
    const int c = blockIdx.x / 16, b0 = (blockIdx.x % 16) * 16;

    const uint4* Ahp = Ah + (size_t)(b0 + lm) * 1152 + q;
    const uint4* Alp = Al + (size_t)(b0 + lm) * 1152 + q;
    const uint4* Bhp = Bh + ((size_t)q * 10 + c) * 16 + lm;
    const uint4* Blp = Bl + ((size_t)q * 10 + c) * 16 + lm;

    v4f acc = {0.f, 0.f, 0.f, 0.f};
    const int kk0 = wave * 72;
    for (int kk = kk0; kk < kk0 + 72; ++kk) {
        bf16x8 ah = __builtin_bit_cast(bf16x8, Ahp[(size_t)kk * 4]);
        bf16x8 al = __builtin_bit_cast(bf16x8, Alp[(size_t)kk * 4]);
        bf16x8 bh = __builtin_bit_cast(bf16x8, Bhp[(size_t)kk * 640]);
        bf16x8 bl = __builtin_bit_cast(bf16x8, Blp[(size_t)kk * 640]);
        acc = __builtin_amdgcn_mfma_f32_16x16x32_bf16(ah, bh, acc, 0, 0, 0);
        acc = __builtin_amdgcn_mfma_f32_16x16x32_bf16(ah, bl, acc, 0, 0, 0);
        acc = __builtin_amdgcn_mfma_f32_16x16x32_bf16(al, bh, acc, 0, 0, 0);
    }
    #pragma unroll
    for (int r = 0; r < 4; ++r) comb[wave][lane][r] = acc[r];
    __syncthreads();
    if (wave == 0) {
        float s[4], sq[4];
        #pragma unroll
        for (int r = 0; r < 4; ++r) {
            s[r] = comb[0][lane][r] + comb[1][lane][r]
                 + comb[2][lane][r] + comb[3][lane][r];
            if (uniform) s[r] *= 0.1f;
            sq[r] = s[r] * s[r];
        }
        // |s|^2 over d = the 16 lanes (lm) of this quad
        #pragma unroll
        for (int m = 1; m < 16; m <<= 1) {
            #pragma unroll
            for (int r = 0; r < 4; ++r) sq[r] += __shfl_xor(sq[r], m);
        }
        #pragma unroll
        for (int r = 0; r < 4; ++r) {
            const float n = sq[r];
            const float v = s[r] * sqrtf(n) / (1.0f + n);
            const int o = ((b0 + q * 4 + r) * 10 + c) * 16 + lm;
            v_buf[o] = v;
            if (last) outb[o] = v;
        }
    }
}

// ---- agree (round-2 proven structure, fp32 loads):
// b_log[r,c] += mean_b sum_d (sum_i W[r,c,d,i]P[b,r,i]) * v[b,c,d]; softmax_c
__global__ __launch_bounds__(192) void agree_kernel(
    const float4* __restrict__ P4, const float4* __restrict__ W4,
    const float* __restrict__ v_buf, float* __restrict__ b_log,
    float* __restrict__ c_coef, int first)
{
    __shared__ float plds[256 * 8];
    __shared__ float sm[10];
    const int tid = threadIdx.x;
    const int r = blockIdx.x;
    for (int u = tid; u < 256; u += 192) {
        float4 a = P4[(size_t)u * 2304 + r * 2];
        float4 b = P4[(size_t)u * 2304 + r * 2 + 1];
        float* p = &plds[u * 8];
        p[0]=a.x; p[1]=a.y; p[2]=a.z; p[3]=a.w;
        p[4]=b.x; p[5]=b.y; p[6]=b.z; p[7]=b.w;
    }
    const int cc = tid >> 4, dv = tid & 15;
    const bool active = tid < 160;
    float wf[8];
    if (active) {
        float4 a = W4[(((size_t)r * 10 + cc) * 16 + dv) * 2];
        float4 b = W4[(((size_t)r * 10 + cc) * 16 + dv) * 2 + 1];
        wf[0]=a.x; wf[1]=a.y; wf[2]=a.z; wf[3]=a.w;
        wf[4]=b.x; wf[5]=b.y; wf[6]=b.z; wf[7]=b.w;
    }
    __syncthreads();

    float acc = 0.f;
    if (active) {
        for (int b = 0; b < 256; ++b) {
            const float* pf = &plds[b * 8];
            float uh = 0.f;
            #pragma unroll
            for (int i = 0; i < 8; ++i) uh = fmaf(pf[i], wf[i], uh);
            acc = fmaf(uh, v_buf[(b * 10 + cc) * 16 + dv], acc);
        }
    }
    acc += __shfl_xor(acc, 1);
    acc += __shfl_xor(acc, 2);
    acc += __shfl_xor(acc, 4);
    acc += __shfl_xor(acc, 8);

    if (active && dv == 0) {
        const float a = acc * (1.0f / 256.0f);
        const float bc = (first ? 0.f : b_log[r * 10 + cc]) + a;
        b_log[r * 10 + cc] = bc;
        sm[cc] = bc;
    }
    __syncthreads();
    if (tid < 10) {
        float m = sm[0];
        #pragma unroll
        for (int j = 1; j < 10; ++j) m = fmaxf(m, sm[j]);
        float den = 0.f;
        #pragma unroll
        for (int j = 0; j < 10; ++j) den += __expf(sm[j] - m);
        c_coef[r * 10 + tid] = __expf(sm[tid] - m) / den;
    }
}

extern "C" void kernel_launch(void* const* d_in, const int* in_sizes, int n_in,
                              void* d_out, int out_size, void* d_ws, size_t ws_size,
                              hipStream_t stream)
{
    const float4* P4 = (const float4*)d_in[0];
    const float4* W4 = (const float4*)d_in[1];
    float* ws = (float*)d_ws;
    // ws layout in f32 units (4 B). Sizes: Ph/Pl = 589824 uint2 = 1179648 f32
    // units EACH; Wh/Wl/Bh/Bl = 368640 uint2 = 737280 f32 units each.
    float* b_log  = ws;                     // 11520
    float* c_coef = ws + 11520;             // 11520
    float* v_buf  = ws + 23040;             // 40960 -> ends 64000
    uint2* Ph = (uint2*)(ws + 65536);       // ends 1245184
    uint2* Pl = (uint2*)(ws + 1310720);     // ends 2490368
    uint2* Wh = (uint2*)(ws + 2621440);     // ends 3358720
    uint2* Wl = (uint2*)(ws + 3407872);     // ends 4145152
    uint2* Bh = (uint2*)(ws + 4194304);     // ends 4931584
    uint2* Bl = (uint2*)(ws + 4980736);     // ends 5718016 (~22.9 MB of ~268 MB)
    float* outb = (float*)d_out;

    split_p_kernel<<<2304, 256, 0, stream>>>(P4, Ph, Pl);
    split_w_kernel<<<1440, 256, 0, stream>>>(W4, Wh, Wl);

    // iter 0: B = W, uniform c = 0.1 applied post-MFMA
    sgemm_kernel<<<160, 256, 0, stream>>>((const uint4*)Ph, (const uint4*)Pl,
                                          (const uint4*)Wh, (const uint4*)Wl,
                                          v_buf, outb, 1, 0);
    agree_kernel<<<1152, 192, 0, stream>>>(P4, W4, v_buf, b_log, c_coef, 1);
    // iter 1
    bc_kernel<<<1440, 256, 0, stream>>>(W4, c_coef, Bh, Bl);
    sgemm_kernel<<<160, 256, 0, stream>>>((const uint4*)Ph, (const uint4*)Pl,
                                          (const uint4*)Bh, (const uint4*)Bl,
                                          v_buf, outb, 0, 0);
    agree_kernel<<<1152, 192, 0, stream>>>(P4, W4, v_buf, b_log, c_coef, 0);
    // iter 2 -> d_out (reference's final logit update is dead)
    bc_kernel<<<1440, 256, 0, stream>>>(W4, c_coef, Bh, Bl);
    sgemm_kernel<<<160, 256, 0, stream>>>((const uint4*)Ph, (const uint4*)Pl,
                                          (const uint4*)Bh, (const uint4*)Bl,
                                          v_buf, outb, 0, 1);
}

// Round 8
// 200.846 us; speedup vs baseline: 1.0556x; 1.0383x over previous
//
#include <hip/hip_runtime.h>
#include <hip/hip_bf16.h>
#include <math.h>

// DigitCaps routing. PROVEN: P/W/out all FP32; MFMA hi/lo split path correct
// (round 7: PASS absmax 1.95e-3). Round 8: agree -> MFMA (tgemm+reduce_bc),
// sgemm 512thr 8-way split-K, v kept only in transposed hi/lo form.
//   P [256][9216] f32, W [1152][10][16][8] f32, out v [256][10][16] f32.

typedef __bf16 bf16x8 __attribute__((ext_vector_type(8)));
typedef float v4f __attribute__((ext_vector_type(4)));

__device__ __forceinline__ float b2f(unsigned short u) {
    return __uint_as_float(((unsigned)u) << 16);
}
__device__ __forceinline__ unsigned short f2b(float f) {   // RNE, finite only
    unsigned x = __float_as_uint(f);
    return (unsigned short)((x + 0x7FFFu + ((x >> 16) & 1u)) >> 16);
}
__device__ __forceinline__ void split4(float4 x, unsigned short* h, unsigned short* l) {
    const float* xf = (const float*)&x;
    #pragma unroll
    for (int i = 0; i < 4; ++i) {
        h[i] = f2b(xf[i]);
        l[i] = f2b(xf[i] - b2f(h[i]));
    }
}
__device__ __forceinline__ uint2 pack4(const unsigned short* s) {
    uint2 w;
    w.x = s[0] | ((unsigned)s[1] << 16);
    w.y = s[2] | ((unsigned)s[3] << 16);
    return w;
}

// ---- split P into hi/lo row planes AND hi/lo transposed planes.
// 64k x 64b tile per block; grid 144*4.
__global__ __launch_bounds__(256) void split_p_kernel(
    const float4* __restrict__ P4, uint2* __restrict__ Ph, uint2* __restrict__ Pl,
    uint4* __restrict__ Pth, uint4* __restrict__ Ptl)
{
    __shared__ unsigned short ldsH[64 * 72];
    __shared__ unsigned short ldsL[64 * 72];
    const int tid = threadIdx.x;
    const int b0 = (blockIdx.x & 3) * 64;
    const int k0 = (blockIdx.x >> 2) * 64;
    #pragma unroll
    for (int j = 0; j < 4; ++j) {
        int idx = tid + j * 256;              // 0..1023
        int row = idx >> 4, col4 = idx & 15;  // b-local, k/4-local
        int g = (b0 + row) * 2304 + (k0 >> 2) + col4;
        unsigned short h[4], l[4];
        split4(P4[g], h, l);
        Ph[g] = pack4(h);
        Pl[g] = pack4(l);
        #pragma unroll
        for (int i = 0; i < 4; ++i) {
            ldsH[(col4 * 4 + i) * 72 + row] = h[i];
            ldsL[(col4 * 4 + i) * 72 + row] = l[i];
        }
    }
    __syncthreads();
    #pragma unroll
    for (int j = 0; j < 2; ++j) {
        int idx = tid + j * 256;              // 0..511
        int krow = idx >> 3, bcol = idx & 7;
        unsigned short h[8], l[8];
        #pragma unroll
        for (int i = 0; i < 8; ++i) {
            h[i] = ldsH[krow * 72 + bcol * 8 + i];
            l[i] = ldsL[krow * 72 + bcol * 8 + i];
        }
        uint4 wh, wl;
        wh.x = h[0] | ((unsigned)h[1] << 16); wh.y = h[2] | ((unsigned)h[3] << 16);
        wh.z = h[4] | ((unsigned)h[5] << 16); wh.w = h[6] | ((unsigned)h[7] << 16);
        wl.x = l[0] | ((unsigned)l[1] << 16); wl.y = l[2] | ((unsigned)l[3] << 16);
        wl.z = l[4] | ((unsigned)l[5] << 16); wl.w = l[6] | ((unsigned)l[7] << 16);
        Pth[(size_t)(k0 + krow) * 32 + (b0 >> 3) + bcol] = wh;
        Ptl[(size_t)(k0 + krow) * 32 + (b0 >> 3) + bcol] = wl;
    }
}

// ---- split W into hi/lo planes ----
__global__ __launch_bounds__(256) void split_w_kernel(
    const float4* __restrict__ W4, uint2* __restrict__ Wh, uint2* __restrict__ Wl)
{
    const int idx = blockIdx.x * 256 + threadIdx.x;    // 0..368639
    unsigned short h[4], l[4];
    split4(W4[idx], h, l);
    Wh[idx] = pack4(h);
    Wl[idx] = pack4(l);
}

// ---- MFMA s-GEMM + fused squash (round-7-proven maps; now 512 thr, K/8 per wave).
// Writes v transposed hi/lo (vt[cd][b]) for tgemm A; last iter writes outb.
__global__ __launch_bounds__(512) void sgemm_kernel(
    const uint4* __restrict__ Ah, const uint4* __restrict__ Al,
    const uint4* __restrict__ Bh, const uint4* __restrict__ Bl,
    uint2* __restrict__ vth, uint2* __restrict__ vtl,
    float* __restrict__ outb, int uniform, int last)
{
    __shared__ float comb[8][64][4];
    const int tid = threadIdx.x;
    const int wave = tid >> 6, lane = tid & 63;
    const int lm = lane & 15, q = lane >> 4;
    const int c = blockIdx.x / 16, b0 = (blockIdx.x % 16) * 16;

    const uint4* Ahp = Ah + (size_t)(b0 + lm) * 1152 + q;
    const uint4* Alp = Al + (size_t)(b0 + lm) * 1152 + q;
    const uint4* Bhp = Bh + ((size_t)q * 10 + c) * 16 + lm;
    const uint4* Blp = Bl + ((size_t)q * 10 + c) * 16 + lm;

    v4f acc = {0.f, 0.f, 0.f, 0.f};
    const int kk0 = wave * 36;
    for (int kk = kk0; kk < kk0 + 36; ++kk) {
        bf16x8 ah = __builtin_bit_cast(bf16x8, Ahp[(size_t)kk * 4]);
        bf16x8 al = __builtin_bit_cast(bf16x8, Alp[(size_t)kk * 4]);
        bf16x8 bh = __builtin_bit_cast(bf16x8, Bhp[(size_t)kk * 640]);
        bf16x8 bl = __builtin_bit_cast(bf16x8, Blp[(size_t)kk * 640]);
        acc = __builtin_amdgcn_mfma_f32_16x16x32_bf16(ah, bh, acc, 0, 0, 0);
        acc = __builtin_amdgcn_mfma_f32_16x16x32_bf16(ah, bl, acc, 0, 0, 0);
        acc = __builtin_amdgcn_mfma_f32_16x16x32_bf16(al, bh, acc, 0, 0, 0);
    }
    #pragma unroll
    for (int r = 0; r < 4; ++r) comb[wave][lane][r] = acc[r];
    __syncthreads();
    if (wave == 0) {
        float s[4], sq[4];
        #pragma unroll
        for (int r = 0; r < 4; ++r) {
            s[r] = 0.f;
            #pragma unroll
            for (int w = 0; w < 8; ++w) s[r] += comb[w][lane][r];
            if (uniform) s[r] *= 0.1f;
            sq[r] = s[r] * s[r];
        }
        #pragma unroll
        for (int m = 1; m < 16; m <<= 1) {
            #pragma unroll
            for (int r = 0; r < 4; ++r) sq[r] += __shfl_xor(sq[r], m);
        }
        float v[4];
        #pragma unroll
        for (int r = 0; r < 4; ++r) {
            const float n = sq[r];
            v[r] = s[r] * sqrtf(n) / (1.0f + n);
        }
        if (!last) {
            unsigned short h[4], l[4];
            #pragma unroll
            for (int r = 0; r < 4; ++r) {
                h[r] = f2b(v[r]);
                l[r] = f2b(v[r] - b2f(h[r]));
            }
            const int o = (c * 16 + lm) * 64 + (b0 >> 2) + q;   // uint2 units
            vth[o] = pack4(h);
            vtl[o] = pack4(l);
        } else {
            #pragma unroll
            for (int r = 0; r < 4; ++r)
                outb[((b0 + q * 4 + r) * 10 + c) * 16 + lm] = v[r];
        }
    }
}

// ---- tgemm: G[cd][ri] = sum_b vt[cd][b] * Pt[ri][b]  (hi/lo, K=256) ----
__global__ __launch_bounds__(256) void tgemm_kernel(
    const uint4* __restrict__ vth, const uint4* __restrict__ vtl,
    const uint4* __restrict__ Pth, const uint4* __restrict__ Ptl,
    float* __restrict__ G)
{
    const int tid = threadIdx.x;
    const int wave = tid >> 6, lane = tid & 63;
    const int lm = lane & 15, q = lane >> 4;
    const int n0 = (blockIdx.x * 4 + wave) * 16;   // 576 ri tiles

    v4f acc[10];
    #pragma unroll
    for (int mt = 0; mt < 10; ++mt) acc[mt] = (v4f){0.f, 0.f, 0.f, 0.f};
    #pragma unroll
    for (int kk = 0; kk < 8; ++kk) {
        bf16x8 bh = __builtin_bit_cast(bf16x8, Pth[(size_t)(n0 + lm) * 32 + kk * 4 + q]);
        bf16x8 bl = __builtin_bit_cast(bf16x8, Ptl[(size_t)(n0 + lm) * 32 + kk * 4 + q]);
        #pragma unroll
        for (int mt = 0; mt < 10; ++mt) {
            bf16x8 ah = __builtin_bit_cast(bf16x8, vth[(size_t)(mt * 16 + lm) * 32 + kk * 4 + q]);
            bf16x8 al = __builtin_bit_cast(bf16x8, vtl[(size_t)(mt * 16 + lm) * 32 + kk * 4 + q]);
            acc[mt] = __builtin_amdgcn_mfma_f32_16x16x32_bf16(ah, bh, acc[mt], 0, 0, 0);
            acc[mt] = __builtin_amdgcn_mfma_f32_16x16x32_bf16(ah, bl, acc[mt], 0, 0, 0);
            acc[mt] = __builtin_amdgcn_mfma_f32_16x16x32_bf16(al, bh, acc[mt], 0, 0, 0);
        }
    }
    #pragma unroll
    for (int mt = 0; mt < 10; ++mt)
        #pragma unroll
        for (int r = 0; r < 4; ++r)
            G[(size_t)(mt * 16 + q * 4 + r) * 9216 + n0 + lm] = acc[mt][r];
}

// ---- reduce_bc: a[r,c] = (1/256) sum_{d,i} W*G ; logits; softmax; emit Bc hi/lo ----
__global__ __launch_bounds__(128) void reduce_bc_kernel(
    const float* __restrict__ Wf, const float* __restrict__ G,
    float* __restrict__ b_log, unsigned short* __restrict__ Bh,
    unsigned short* __restrict__ Bl, int first)
{
    __shared__ float part[2][10];
    __shared__ float cl[10];
    const int t = threadIdx.x;          // 0..127 = d*8+i
    const int r = blockIdx.x;
    const int wid = t >> 6, lane = t & 63;

    float wv[10], a[10];
    #pragma unroll
    for (int c = 0; c < 10; ++c) {
        wv[c] = Wf[((size_t)r * 10 + c) * 128 + t];
        float g = G[(size_t)(c * 16 + (t >> 3)) * 9216 + r * 8 + (t & 7)];
        a[c] = wv[c] * g;
    }
    #pragma unroll
    for (int m = 1; m < 64; m <<= 1) {
        #pragma unroll
        for (int c = 0; c < 10; ++c) a[c] += __shfl_xor(a[c], m);
    }
    if (lane == 0) {
        #pragma unroll
        for (int c = 0; c < 10; ++c) part[wid][c] = a[c];
    }
    __syncthreads();
    if (t < 10) {
        float s_ = (part[0][t] + part[1][t]) * (1.0f / 256.0f);
        float bn = (first ? 0.f : b_log[r * 10 + t]) + s_;
        b_log[r * 10 + t] = bn;
        part[0][t] = bn;                 // reuse as softmax scratch
    }
    __syncthreads();
    if (t < 10) {
        float mx = part[0][0];
        #pragma unroll
        for (int j = 1; j < 10; ++j) mx = fmaxf(mx, part[0][j]);
        float den = 0.f;
        #pragma unroll
        for (int j = 0; j < 10; ++j) den += __expf(part[0][j] - mx);
        cl[t] = __expf(part[0][t] - mx) / den;
    }
    __syncthreads();
    #pragma unroll
    for (int c = 0; c < 10; ++c) {
        float x = cl[c] * wv[c];
        unsigned short h = f2b(x);
        Bh[((size_t)r * 10 + c) * 128 + t] = h;
        Bl[((size_t)r * 10 + c) * 128 + t] = f2b(x - b2f(h));
    }
}

extern "C" void kernel_launch(void* const* d_in, const int* in_sizes, int n_in,
                              void* d_out, int out_size, void* d_ws, size_t ws_size,
                              hipStream_t stream)
{
    const float4* P4 = (const float4*)d_in[0];
    const float4* W4 = (const float4*)d_in[1];
    char* wsb = (char*)d_ws;
    // BYTE offsets (audited, all 16B-aligned, total ~43.6 MB of ~268 MB):
    float* b_log = (float*)(wsb + 0);              // 46080 B
    uint2* vth   = (uint2*)(wsb + 131072);         // 81920 B
    uint2* vtl   = (uint2*)(wsb + 262144);         // 81920 B
    uint2* Ph    = (uint2*)(wsb + 393216);         // 4718592 B
    uint2* Pl    = (uint2*)(wsb + 5242880);        // 4718592 B
    uint4* Pth   = (uint4*)(wsb + 10485760);       // 4718592 B
    uint4* Ptl   = (uint4*)(wsb + 15728640);       // 4718592 B
    uint2* Wh    = (uint2*)(wsb + 20971520);       // 2949120 B
    uint2* Wl    = (uint2*)(wsb + 25165824);       // 2949120 B
    unsigned short* Bh = (unsigned short*)(wsb + 29360128);  // 2949120 B
    unsigned short* Bl = (unsigned short*)(wsb + 33554432);  // 2949120 B
    float* G     = (float*)(wsb + 37748736);       // 5898240 B -> ends 43646976
    float* outb  = (float*)d_out;
    const float* Wf = (const float*)W4;

    split_p_kernel<<<576, 256, 0, stream>>>(P4, Ph, Pl, Pth, Ptl);
    split_w_kernel<<<1440, 256, 0, stream>>>(W4, Wh, Wl);

    // iter 0: B = W, uniform c = 0.1 post-MFMA
    sgemm_kernel<<<160, 512, 0, stream>>>((const uint4*)Ph, (const uint4*)Pl,
                                          (const uint4*)Wh, (const uint4*)Wl,
                                          vth, vtl, outb, 1, 0);
    tgemm_kernel<<<144, 256, 0, stream>>>((const uint4*)vth, (const uint4*)vtl,
                                          Pth, Ptl, G);
    reduce_bc_kernel<<<1152, 128, 0, stream>>>(Wf, G, b_log, Bh, Bl, 1);
    // iter 1
    sgemm_kernel<<<160, 512, 0, stream>>>((const uint4*)Ph, (const uint4*)Pl,
                                          (const uint4*)Bh, (const uint4*)Bl,
                                          vth, vtl, outb, 0, 0);
    tgemm_kernel<<<144, 256, 0, stream>>>((const uint4*)vth, (const uint4*)vtl,
                                          Pth, Ptl, G);
    reduce_bc_kernel<<<1152, 128, 0, stream>>>(Wf, G, b_log, Bh, Bl, 0);
    // iter 2 -> d_out
    sgemm_kernel<<<160, 512, 0, stream>>>((const uint4*)Ph, (const uint4*)Pl,
                                          (const uint4*)Bh, (const uint4*)Bl,
                                          vth, vtl, outb, 0, 1);
}